// Round 1
// baseline (272.686 us; speedup 1.0000x reference)
//
#include <hip/hip_runtime.h>
#include <math.h>

// FourierConv2D: B=16,H=W=128,C=16,F=32. FFT size 256x256, half-spectrum w in [0,129).
// out[b,y',x',f] = Re( (1/65536) * sum_{h,w} c_w * (sum_c Fimg[b,h,w,c]*K[h,w,f,c]) * e^{+2pi i (h(y'+63)+w(x'+63))/256} )
// implemented as: rowFFT -> colFFT -> pointwise einsum -> col iFFT (crop y) -> Hermitian-extend row iFFT (crop x, Re).

constexpr int Bn = 16, Cc = 16, Ff = 32, Hh = 128, Ww = 128, Nn = 256, WH = 129;

#define DEVINL __device__ __forceinline__

DEVINL float2 f2(float a, float b) { return make_float2(a, b); }

// ---- in-register 16-point FFT, SGN=-1 forward (e^{-2pi i}), SGN=+1 inverse (unnormalized) ----
template<int SGN>
DEVINL void fft16r(float2 v[16]) {
  float2 t;
#define SW(a,b) { t = v[a]; v[a] = v[b]; v[b] = t; }
  SW(1, 8) SW(2, 4) SW(3, 12) SW(5, 10) SW(7, 14) SW(11, 13)
#undef SW
  const float C1 = 0.92387953251128674f, C2 = 0.70710678118654752f, C3 = 0.38268343236508977f;
  const float Ct[8] = {1.f, C1, C2, C3, 0.f, -C3, -C2, -C1};
  const float St[8] = {0.f, C3, C2, C1, 1.f, C1, C2, C3};
#pragma unroll
  for (int len = 2; len <= 16; len <<= 1) {
    const int half = len >> 1, ts = 16 / len;
#pragma unroll
    for (int i = 0; i < 16; i += len) {
#pragma unroll
      for (int j = 0; j < half; ++j) {
        const float wr = Ct[j * ts];
        const float wi = (SGN > 0) ? St[j * ts] : -St[j * ts];
        float2 b = v[i + j + half];
        float2 tt = f2(wr * b.x - wi * b.y, wr * b.y + wi * b.x);
        float2 a = v[i + j];
        v[i + j]        = f2(a.x + tt.x, a.y + tt.y);
        v[i + j + half] = f2(a.x - tt.x, a.y - tt.y);
      }
    }
  }
}

// ---- cooperative 256-pt FFT: 16 threads per FFT, data in sf[0..255] (natural order in & out) ----
// w256[j] = exp(-2pi i j / 256)
template<int SGN>
DEVINL void fft256_coop(float2* __restrict__ sf, const float2* __restrict__ w256, int t) {
  __syncthreads();                       // caller's writes visible
  float2 v[16];
#pragma unroll
  for (int n1 = 0; n1 < 16; ++n1) v[n1] = sf[t + 16 * n1];   // n = n2 + 16*n1, n2 = t
  fft16r<SGN>(v);                        // v[k1] = Y[n2,k1]
#pragma unroll
  for (int k = 1; k < 16; ++k) {         // twiddle W256^{SGN * n2 * k1}
    float2 w = w256[(t * k) & 255];
    if (SGN > 0) w.y = -w.y;
    v[k] = f2(v[k].x * w.x - v[k].y * w.y, v[k].x * w.y + v[k].y * w.x);
  }
  __syncthreads();                       // all reads done before overwrite
#pragma unroll
  for (int k = 0; k < 16; ++k) sf[t * 16 + k] = v[k];        // Z[n2][k1]
  __syncthreads();
  float2 u[16];
#pragma unroll
  for (int n2 = 0; n2 < 16; ++n2) u[n2] = sf[n2 * 16 + t];   // Z[:, k1=t]
  fft16r<SGN>(u);                        // u[k2] = X[t + 16*k2]
  __syncthreads();                       // reads done before overwrite
#pragma unroll
  for (int k2 = 0; k2 < 16; ++k2) sf[t + 16 * k2] = u[k2];   // natural order
  __syncthreads();
}

DEVINL void init_w256(float2* w256) {
  const int tid = threadIdx.x;           // blocks are exactly 256 threads
  double ang = -2.0 * M_PI * (double)tid / 256.0;
  w256[tid] = make_float2((float)cos(ang), (float)sin(ang));
}

// ---- K1: per (b,y): 16 row FFTs over x (zero-padded 128->256), keep w in [0,129) ----
// R layout: [b][w][y][c]
__global__ __launch_bounds__(256) void k1_rowfft(const float* __restrict__ img, float2* __restrict__ R) {
  __shared__ float2 s[16][260];
  __shared__ float2 w256[256];
  const int tid = threadIdx.x;
  const int y = blockIdx.x, b = blockIdx.y;
  init_w256(w256);
  const float* ip = img + ((size_t)(b * Hh + y) * Ww) * Cc;
  for (int i = tid; i < Ww * Cc; i += 256) { int x = i >> 4, c = i & 15; s[c][x] = f2(ip[i], 0.f); }
  for (int i = tid; i < Ww * Cc; i += 256) { int x = (i >> 4) + 128, c = i & 15; s[c][x] = f2(0.f, 0.f); }
  fft256_coop<-1>(&s[tid >> 4][0], w256, tid & 15);
  for (int i = tid; i < WH * Cc; i += 256) {
    int w = i >> 4, c = i & 15;
    R[(((size_t)b * WH + w) * Hh + y) * Cc + c] = s[c][w];
  }
}

// ---- K2: per (b,w): 16 column FFTs over y (zero-padded 128->256) ----
// Fimg layout: [h][w][b][c]
__global__ __launch_bounds__(256) void k2_colfft(const float2* __restrict__ R, float2* __restrict__ Fimg) {
  __shared__ float2 s[16][260];
  __shared__ float2 w256[256];
  const int tid = threadIdx.x;
  const int w = blockIdx.x, b = blockIdx.y;
  init_w256(w256);
  const float2* rp = R + ((size_t)b * WH + w) * Hh * Cc;
  for (int i = tid; i < Hh * Cc; i += 256) { int y = i >> 4, c = i & 15; s[c][y] = rp[i]; }
  for (int i = tid; i < Hh * Cc; i += 256) { int y = (i >> 4) + 128, c = i & 15; s[c][y] = f2(0.f, 0.f); }
  fft256_coop<-1>(&s[tid >> 4][0], w256, tid & 15);
  for (int i = tid; i < Nn * Cc; i += 256) {
    int h = i >> 4, c = i & 15;
    Fimg[(((size_t)h * WH + w) * Bn + b) * Cc + c] = s[c][h];
  }
}

// ---- K3: per (h,w): out_f[b,f] = sum_c Fimg[b,c] * (Kr[f,c] + i Ki[f,c]) ----
// OF layout: [w][h][b][f]
__global__ __launch_bounds__(256) void k3_mul(const float2* __restrict__ Fimg, const float* __restrict__ Kr,
                                              const float* __restrict__ Ki, float2* __restrict__ OF) {
  __shared__ float2 A[256];      // [b*16+c]
  __shared__ float kr[16][33];   // [c][f] padded
  __shared__ float ki[16][33];
  const int tid = threadIdx.x;
  const int w = blockIdx.x, h = blockIdx.y;
  const size_t fo = ((size_t)h * WH + w) * 256;
  A[tid] = Fimg[fo + tid];
  const size_t ko = ((size_t)h * WH + w) * 512;
  for (int i = tid; i < 512; i += 256) {
    int f = i >> 4, c = i & 15;
    kr[c][f] = Kr[ko + i];
    ki[c][f] = Ki[ko + i];
  }
  __syncthreads();
  const int b0 = tid >> 5;       // 0..7  (handles b0 and b0+8)
  const int f0 = tid & 31;
  float2 acc0 = f2(0.f, 0.f), acc1 = f2(0.f, 0.f);
#pragma unroll
  for (int c = 0; c < 16; ++c) {
    const float krv = kr[c][f0], kiv = ki[c][f0];
    const float2 a0 = A[b0 * 16 + c];
    const float2 a1 = A[(b0 + 8) * 16 + c];
    acc0.x += a0.x * krv - a0.y * kiv;  acc0.y += a0.x * kiv + a0.y * krv;
    acc1.x += a1.x * krv - a1.y * kiv;  acc1.y += a1.x * kiv + a1.y * krv;
  }
  float2* op = OF + ((size_t)w * 256 + h) * 512;
  op[tid] = acc0;
  op[tid + 256] = acc1;
}

// ---- K4: per (b,w,fg): 16 inverse column FFTs over h; store only y in [63,191) ----
// T layout: [b][y'][w][f]
__global__ __launch_bounds__(256) void k4_colifft(const float2* __restrict__ OF, float2* __restrict__ T) {
  __shared__ float2 s[16][260];
  __shared__ float2 w256[256];
  const int tid = threadIdx.x;
  const int w = blockIdx.x, b = blockIdx.y, fg = blockIdx.z;
  init_w256(w256);
  const float2* ofp = OF + (size_t)w * 256 * 512 + (size_t)b * 32 + (size_t)fg * 16;
  for (int i = tid; i < Nn * 16; i += 256) {
    int h = i >> 4, fl = i & 15;
    s[fl][h] = ofp[(size_t)h * 512 + fl];
  }
  fft256_coop<1>(&s[tid >> 4][0], w256, tid & 15);
  float2* tp = T + ((size_t)b * Hh * WH + w) * Ff + (size_t)fg * 16;
  for (int i = tid; i < Hh * 16; i += 256) {
    int yp = i >> 4, fl = i & 15;
    tp[(size_t)yp * WH * Ff + fl] = s[fl][63 + yp];
  }
}

// ---- K5: per (b,y',fg): Hermitian-extend w-spectrum, inverse FFT, Re, scale, +bias, crop x ----
__global__ __launch_bounds__(256) void k5_rowifft(const float2* __restrict__ T, const float* __restrict__ bias,
                                                  float* __restrict__ out) {
  __shared__ float2 s[16][260];
  __shared__ float2 w256[256];
  const int tid = threadIdx.x;
  const int yp = blockIdx.x, b = blockIdx.y, fg = blockIdx.z;
  init_w256(w256);
  const float2* tp = T + ((size_t)b * Hh + yp) * WH * Ff + (size_t)fg * 16;
  for (int i = tid; i < WH * 16; i += 256) {
    int w = i >> 4, fl = i & 15;
    s[fl][w] = tp[(size_t)w * Ff + fl];
  }
  __syncthreads();
  for (int i = tid; i < 127 * 16; i += 256) {   // V[w2] = conj(V[256-w2]), w2 in [129,255]
    int w2 = 129 + (i >> 4), fl = i & 15;
    float2 z = s[fl][256 - w2];
    s[fl][w2] = f2(z.x, -z.y);
  }
  fft256_coop<1>(&s[tid >> 4][0], w256, tid & 15);
  const float sc = 1.f / 65536.f;
  const float bv = bias[fg * 16 + (tid & 15)];  // fl is invariant across the store loop
  float* op = out + ((size_t)b * Hh + yp) * Ww * Ff + fg * 16;
  for (int i = tid; i < Ww * 16; i += 256) {
    int xp = i >> 4, fl = i & 15;
    op[(size_t)xp * Ff + fl] = s[fl][63 + xp].x * sc + bv;
  }
}

extern "C" void kernel_launch(void* const* d_in, const int* in_sizes, int n_in,
                              void* d_out, int out_size, void* d_ws, size_t ws_size,
                              hipStream_t stream) {
  const float* img  = (const float*)d_in[0];
  const float* kr   = (const float*)d_in[1];
  const float* ki   = (const float*)d_in[2];
  const float* bias = (const float*)d_in[3];
  float* out = (float*)d_out;

  char* ws = (char*)d_ws;
  // region layout (lifetime-overlapped):
  //   [0, 67.6MB):            Fimg (K2->K3), later T (K4->K5)   (same size: 8,454,144 float2)
  //   [67.6MB, 203MB):        OF  (K3->K4);  R (K1->K2) aliases its head (dead before K3)
  const size_t szF = (size_t)Nn * WH * Bn * Cc * sizeof(float2);   // 67,633,152
  float2* Fimg = (float2*)ws;
  float2* T    = (float2*)ws;
  float2* OF   = (float2*)(ws + szF);
  float2* R    = (float2*)(ws + szF);

  k1_rowfft <<<dim3(Hh, Bn),    256, 0, stream>>>(img, R);
  k2_colfft <<<dim3(WH, Bn),    256, 0, stream>>>(R, Fimg);
  k3_mul    <<<dim3(WH, Nn),    256, 0, stream>>>(Fimg, kr, ki, OF);
  k4_colifft<<<dim3(WH, Bn, 2), 256, 0, stream>>>(OF, T);
  k5_rowifft<<<dim3(Hh, Bn, 2), 256, 0, stream>>>(T, bias, out);
}

// Round 2
// 236.644 us; speedup vs baseline: 1.1523x; 1.1523x over previous
//
#include <hip/hip_runtime.h>
#include <math.h>

// FourierConv2D: B=16,H=W=128,C=16,F=32. FFT size 256x256, half-spectrum w in [0,129).
// rowFFT -> colFFT -> pointwise einsum (double-buffered, 8 pts/block) -> col iFFT (crop y)
// -> Hermitian-extend row iFFT (crop x, Re).

constexpr int Bn = 16, Cc = 16, Ff = 32, Hh = 128, Ww = 128, Nn = 256, WH = 129;

#define DEVINL __device__ __forceinline__

DEVINL float2 f2(float a, float b) { return make_float2(a, b); }

// ---- in-register 16-point FFT, SGN=-1 forward, SGN=+1 inverse (unnormalized) ----
template<int SGN>
DEVINL void fft16r(float2 v[16]) {
  float2 t;
#define SW(a,b) { t = v[a]; v[a] = v[b]; v[b] = t; }
  SW(1, 8) SW(2, 4) SW(3, 12) SW(5, 10) SW(7, 14) SW(11, 13)
#undef SW
  const float C1 = 0.92387953251128674f, C2 = 0.70710678118654752f, C3 = 0.38268343236508977f;
  const float Ct[8] = {1.f, C1, C2, C3, 0.f, -C3, -C2, -C1};
  const float St[8] = {0.f, C3, C2, C1, 1.f, C1, C2, C3};
#pragma unroll
  for (int len = 2; len <= 16; len <<= 1) {
    const int half = len >> 1, ts = 16 / len;
#pragma unroll
    for (int i = 0; i < 16; i += len) {
#pragma unroll
      for (int j = 0; j < half; ++j) {
        const float wr = Ct[j * ts];
        const float wi = (SGN > 0) ? St[j * ts] : -St[j * ts];
        float2 b = v[i + j + half];
        float2 tt = f2(wr * b.x - wi * b.y, wr * b.y + wi * b.x);
        float2 a = v[i + j];
        v[i + j]        = f2(a.x + tt.x, a.y + tt.y);
        v[i + j + half] = f2(a.x - tt.x, a.y - tt.y);
      }
    }
  }
}

// ---- cooperative 256-pt FFT: 16 threads per FFT, data in sf[0..255] (natural order in & out) ----
template<int SGN>
DEVINL void fft256_coop(float2* __restrict__ sf, const float2* __restrict__ w256, int t) {
  __syncthreads();
  float2 v[16];
#pragma unroll
  for (int n1 = 0; n1 < 16; ++n1) v[n1] = sf[t + 16 * n1];
  fft16r<SGN>(v);
#pragma unroll
  for (int k = 1; k < 16; ++k) {
    float2 w = w256[(t * k) & 255];
    if (SGN > 0) w.y = -w.y;
    v[k] = f2(v[k].x * w.x - v[k].y * w.y, v[k].x * w.y + v[k].y * w.x);
  }
  __syncthreads();
#pragma unroll
  for (int k = 0; k < 16; ++k) sf[t * 16 + k] = v[k];
  __syncthreads();
  float2 u[16];
#pragma unroll
  for (int n2 = 0; n2 < 16; ++n2) u[n2] = sf[n2 * 16 + t];
  fft16r<SGN>(u);
  __syncthreads();
#pragma unroll
  for (int k2 = 0; k2 < 16; ++k2) sf[t + 16 * k2] = u[k2];
  __syncthreads();
}

DEVINL void init_w256(float2* w256) {
  const int tid = threadIdx.x;
  double ang = -2.0 * M_PI * (double)tid / 256.0;
  w256[tid] = make_float2((float)cos(ang), (float)sin(ang));
}

// ---- K1: per (b,y): 16 row FFTs over x (zero-padded 128->256), keep w in [0,129) ----
// R layout: [b][w][y][c]
__global__ __launch_bounds__(256) void k1_rowfft(const float* __restrict__ img, float2* __restrict__ R) {
  __shared__ float2 s[16][260];
  __shared__ float2 w256[256];
  const int tid = threadIdx.x;
  const int y = blockIdx.x, b = blockIdx.y;
  init_w256(w256);
  const float* ip = img + ((size_t)(b * Hh + y) * Ww) * Cc;
  for (int i = tid; i < Ww * Cc; i += 256) { int x = i >> 4, c = i & 15; s[c][x] = f2(ip[i], 0.f); }
  for (int i = tid; i < Ww * Cc; i += 256) { int x = (i >> 4) + 128, c = i & 15; s[c][x] = f2(0.f, 0.f); }
  fft256_coop<-1>(&s[tid >> 4][0], w256, tid & 15);
  for (int i = tid; i < WH * Cc; i += 256) {
    int w = i >> 4, c = i & 15;
    R[(((size_t)b * WH + w) * Hh + y) * Cc + c] = s[c][w];
  }
}

// ---- K2: per (b,w): 16 column FFTs over y (zero-padded 128->256) ----
// Fimg layout: [h][w][b][c]
__global__ __launch_bounds__(256) void k2_colfft(const float2* __restrict__ R, float2* __restrict__ Fimg) {
  __shared__ float2 s[16][260];
  __shared__ float2 w256[256];
  const int tid = threadIdx.x;
  const int w = blockIdx.x, b = blockIdx.y;
  init_w256(w256);
  const float2* rp = R + ((size_t)b * WH + w) * Hh * Cc;
  for (int i = tid; i < Hh * Cc; i += 256) { int y = i >> 4, c = i & 15; s[c][y] = rp[i]; }
  for (int i = tid; i < Hh * Cc; i += 256) { int y = (i >> 4) + 128, c = i & 15; s[c][y] = f2(0.f, 0.f); }
  fft256_coop<-1>(&s[tid >> 4][0], w256, tid & 15);
  for (int i = tid; i < Nn * Cc; i += 256) {
    int h = i >> 4, c = i & 15;
    Fimg[(((size_t)h * WH + w) * Bn + b) * Cc + c] = s[c][h];
  }
}

// ---- K3: per (h,w): out_f[b,f] = sum_c Fimg[b,c] * (Kr[f,c] + i Ki[f,c]) ----
// v2: 8 h-points per block, LDS double-buffered with register prefetch.
// OF layout: [w][h][b][f]
constexpr int GP = 8;
__global__ __launch_bounds__(256) void k3_mul(const float2* __restrict__ Fimg, const float* __restrict__ Kr,
                                              const float* __restrict__ Ki, float2* __restrict__ OF) {
  __shared__ float2 A[2][256];   // [b*16+c]
  __shared__ float kr[2][16][33]; // [c][f] padded
  __shared__ float ki[2][16][33];
  const int tid = threadIdx.x;
  const int w = blockIdx.x, h0 = blockIdx.y * GP;
  const int b0 = tid >> 5;       // 0..7 (handles b0 and b0+8)
  const int f0 = tid & 31;
  const int cS = tid & 15, fS = tid >> 4;   // staging decomposition

  float2 aReg;
  float krA, krB, kiA, kiB;

  auto load_regs = [&](int g) {
    const size_t base = (size_t)(h0 + g) * WH + w;
    aReg = Fimg[base * 256 + tid];
    const size_t ko = base * 512;
    krA = Kr[ko + tid]; krB = Kr[ko + tid + 256];
    kiA = Ki[ko + tid]; kiB = Ki[ko + tid + 256];
  };
  auto write_lds = [&](int bb) {
    A[bb][tid] = aReg;
    kr[bb][cS][fS] = krA;  kr[bb][cS][fS + 16] = krB;
    ki[bb][cS][fS] = kiA;  ki[bb][cS][fS + 16] = kiB;
  };

  load_regs(0);
  write_lds(0);
#pragma unroll
  for (int g = 0; g < GP; ++g) {
    const int cur = g & 1;
    if (g + 1 < GP) load_regs(g + 1);   // issue next point's loads early
    __syncthreads();                     // lds[cur] visible
    float2 acc0 = f2(0.f, 0.f), acc1 = f2(0.f, 0.f);
#pragma unroll
    for (int c = 0; c < 16; ++c) {
      const float krv = kr[cur][c][f0], kiv = ki[cur][c][f0];
      const float2 a0 = A[cur][b0 * 16 + c];
      const float2 a1 = A[cur][(b0 + 8) * 16 + c];
      acc0.x += a0.x * krv - a0.y * kiv;  acc0.y += a0.x * kiv + a0.y * krv;
      acc1.x += a1.x * krv - a1.y * kiv;  acc1.y += a1.x * kiv + a1.y * krv;
    }
    float2* op = OF + ((size_t)w * 256 + (h0 + g)) * 512;
    op[tid] = acc0;
    op[tid + 256] = acc1;
    if (g + 1 < GP) write_lds(cur ^ 1); // regs -> other buffer (sync'd by next iter)
  }
}

// ---- K4: per (b,w,fg): 16 inverse column FFTs over h; store only y in [63,191) ----
// T layout: [b][y'][w][f]
__global__ __launch_bounds__(256) void k4_colifft(const float2* __restrict__ OF, float2* __restrict__ T) {
  __shared__ float2 s[16][260];
  __shared__ float2 w256[256];
  const int tid = threadIdx.x;
  const int w = blockIdx.x, b = blockIdx.y, fg = blockIdx.z;
  init_w256(w256);
  const float2* ofp = OF + (size_t)w * 256 * 512 + (size_t)b * 32 + (size_t)fg * 16;
  for (int i = tid; i < Nn * 16; i += 256) {
    int h = i >> 4, fl = i & 15;
    s[fl][h] = ofp[(size_t)h * 512 + fl];
  }
  fft256_coop<1>(&s[tid >> 4][0], w256, tid & 15);
  float2* tp = T + ((size_t)b * Hh * WH + w) * Ff + (size_t)fg * 16;
  for (int i = tid; i < Hh * 16; i += 256) {
    int yp = i >> 4, fl = i & 15;
    tp[(size_t)yp * WH * Ff + fl] = s[fl][63 + yp];
  }
}

// ---- K5: per (b,y',fg): Hermitian-extend w-spectrum, inverse FFT, Re, scale, +bias, crop x ----
__global__ __launch_bounds__(256) void k5_rowifft(const float2* __restrict__ T, const float* __restrict__ bias,
                                                  float* __restrict__ out) {
  __shared__ float2 s[16][260];
  __shared__ float2 w256[256];
  const int tid = threadIdx.x;
  const int yp = blockIdx.x, b = blockIdx.y, fg = blockIdx.z;
  init_w256(w256);
  const float2* tp = T + ((size_t)b * Hh + yp) * WH * Ff + (size_t)fg * 16;
  for (int i = tid; i < WH * 16; i += 256) {
    int w = i >> 4, fl = i & 15;
    s[fl][w] = tp[(size_t)w * Ff + fl];
  }
  __syncthreads();
  for (int i = tid; i < 127 * 16; i += 256) {   // V[w2] = conj(V[256-w2]), w2 in [129,255]
    int w2 = 129 + (i >> 4), fl = i & 15;
    float2 z = s[fl][256 - w2];
    s[fl][w2] = f2(z.x, -z.y);
  }
  fft256_coop<1>(&s[tid >> 4][0], w256, tid & 15);
  const float sc = 1.f / 65536.f;
  const float bv = bias[fg * 16 + (tid & 15)];
  float* op = out + ((size_t)b * Hh + yp) * Ww * Ff + fg * 16;
  for (int i = tid; i < Ww * 16; i += 256) {
    int xp = i >> 4, fl = i & 15;
    op[(size_t)xp * Ff + fl] = s[fl][63 + xp].x * sc + bv;
  }
}

extern "C" void kernel_launch(void* const* d_in, const int* in_sizes, int n_in,
                              void* d_out, int out_size, void* d_ws, size_t ws_size,
                              hipStream_t stream) {
  const float* img  = (const float*)d_in[0];
  const float* kr   = (const float*)d_in[1];
  const float* ki   = (const float*)d_in[2];
  const float* bias = (const float*)d_in[3];
  float* out = (float*)d_out;

  char* ws = (char*)d_ws;
  // region layout (lifetime-overlapped):
  //   [0, 67.6MB):     Fimg (K2->K3), later T (K4->K5)
  //   [67.6MB, 203MB): OF (K3->K4);  R (K1->K2) aliases its head (dead before K3)
  const size_t szF = (size_t)Nn * WH * Bn * Cc * sizeof(float2);   // 67,633,152
  float2* Fimg = (float2*)ws;
  float2* T    = (float2*)ws;
  float2* OF   = (float2*)(ws + szF);
  float2* R    = (float2*)(ws + szF);

  k1_rowfft <<<dim3(Hh, Bn),       256, 0, stream>>>(img, R);
  k2_colfft <<<dim3(WH, Bn),       256, 0, stream>>>(R, Fimg);
  k3_mul    <<<dim3(WH, Nn / GP),  256, 0, stream>>>(Fimg, kr, ki, OF);
  k4_colifft<<<dim3(WH, Bn, 2),    256, 0, stream>>>(OF, T);
  k5_rowifft<<<dim3(Hh, Bn, 2),    256, 0, stream>>>(T, bias, out);
}